// Round 4
// baseline (265.422 us; speedup 1.0000x reference)
//
#include <hip/hip_runtime.h>
#include <math.h>

#define C 4096

// ---------------------------------------------------------------------------
// Kernel 1: fused [token-shift mix] + [kw@xk, vw@xv, rw@xr] + [wkv elementwise].
// Grid: 512 blocks x 256. Block b owns rows R=8b..8b+7 of ALL THREE matrices.
// Wave w (of 4): col-half h=w&1, row-group rg=w>>1 -> 4 rows x 3 mats x 2048
// cols = 12 independent load streams per wave -> ~12-24 outstanding 16B loads
// per wave (MLP from structure, not scheduler hints).
// Since the block owns rows R..R+7 of kk/vv/rr, the WKV elementwise math for
// those rows happens in-block: no intermediate kk/vv/rr round-trip, one less
// kernel + gap.
// ---------------------------------------------------------------------------
__global__ __launch_bounds__(256) void fused_kvr_wkv_kernel(
    const float* __restrict__ kw, const float* __restrict__ vw, const float* __restrict__ rw,
    const float* __restrict__ x, const float* __restrict__ state,
    const float* __restrict__ tmk, const float* __restrict__ tmv, const float* __restrict__ tmr,
    const float* __restrict__ aa, const float* __restrict__ bb, const float* __restrict__ pp,
    const float* __restrict__ time_first, const float* __restrict__ time_decay,
    float* __restrict__ rwkv, float* __restrict__ new_state,
    float* __restrict__ out_sa, float* __restrict__ out_sb, float* __restrict__ out_sp)
{
    __shared__ float4 xsk[C / 4];   // 16 KiB mixed-k vector
    __shared__ float4 xsv[C / 4];   // 16 KiB mixed-v vector
    __shared__ float4 xsr[C / 4];   // 16 KiB mixed-r vector
    __shared__ float  part[3][8][2];

    const int t = threadIdx.x;
    const int R = blockIdx.x * 8;

    // Stage all three mixed vectors: xm = s + m*(x - s)
    const float4* x4  = (const float4*)x;
    const float4* s4  = (const float4*)state;
    const float4* tk4 = (const float4*)tmk;
    const float4* tv4 = (const float4*)tmv;
    const float4* tr4 = (const float4*)tmr;
#pragma unroll
    for (int j = 0; j < 4; ++j) {
        int i = j * 256 + t;
        float4 xi = x4[i], si = s4[i];
        float4 mk = tk4[i], mv = tv4[i], mr = tr4[i];
        float4 rk, rv, rr;
        rk.x = si.x + mk.x * (xi.x - si.x);
        rk.y = si.y + mk.y * (xi.y - si.y);
        rk.z = si.z + mk.z * (xi.z - si.z);
        rk.w = si.w + mk.w * (xi.w - si.w);
        rv.x = si.x + mv.x * (xi.x - si.x);
        rv.y = si.y + mv.y * (xi.y - si.y);
        rv.z = si.z + mv.z * (xi.z - si.z);
        rv.w = si.w + mv.w * (xi.w - si.w);
        rr.x = si.x + mr.x * (xi.x - si.x);
        rr.y = si.y + mr.y * (xi.y - si.y);
        rr.z = si.z + mr.z * (xi.z - si.z);
        rr.w = si.w + mr.w * (xi.w - si.w);
        xsk[i] = rk; xsv[i] = rv; xsr[i] = rr;
    }
    __syncthreads();

    const int wave = t >> 6;
    const int lane = t & 63;
    const int h    = wave & 1;       // column half
    const int rg   = wave >> 1;      // row group (0: rows R..R+3, 1: rows R+4..R+7)
    const int r0   = R + rg * 4;

    const float4* pk0 = (const float4*)(kw + (size_t)(r0 + 0) * C);
    const float4* pk1 = (const float4*)(kw + (size_t)(r0 + 1) * C);
    const float4* pk2 = (const float4*)(kw + (size_t)(r0 + 2) * C);
    const float4* pk3 = (const float4*)(kw + (size_t)(r0 + 3) * C);
    const float4* pv0 = (const float4*)(vw + (size_t)(r0 + 0) * C);
    const float4* pv1 = (const float4*)(vw + (size_t)(r0 + 1) * C);
    const float4* pv2 = (const float4*)(vw + (size_t)(r0 + 2) * C);
    const float4* pv3 = (const float4*)(vw + (size_t)(r0 + 3) * C);
    const float4* pr0 = (const float4*)(rw + (size_t)(r0 + 0) * C);
    const float4* pr1 = (const float4*)(rw + (size_t)(r0 + 1) * C);
    const float4* pr2 = (const float4*)(rw + (size_t)(r0 + 2) * C);
    const float4* pr3 = (const float4*)(rw + (size_t)(r0 + 3) * C);

    float ak0 = 0.f, ak1 = 0.f, ak2 = 0.f, ak3 = 0.f;
    float av0 = 0.f, av1 = 0.f, av2 = 0.f, av3 = 0.f;
    float ar0 = 0.f, ar1 = 0.f, ar2 = 0.f, ar3 = 0.f;

    const int cb0 = h * 512 + lane;
#pragma unroll 2
    for (int it = 0; it < 8; ++it) {
        const int cb = cb0 + it * 64;
        // 12 independent global loads (different rows/matrices) issued together
        float4 wk0 = pk0[cb]; float4 wk1 = pk1[cb]; float4 wk2 = pk2[cb]; float4 wk3 = pk3[cb];
        float4 wv0 = pv0[cb]; float4 wv1 = pv1[cb]; float4 wv2 = pv2[cb]; float4 wv3 = pv3[cb];
        float4 wr0 = pr0[cb]; float4 wr1 = pr1[cb]; float4 wr2 = pr2[cb]; float4 wr3 = pr3[cb];
        float4 xk_ = xsk[cb]; float4 xv_ = xsv[cb]; float4 xr_ = xsr[cb];
        ak0 += wk0.x * xk_.x + wk0.y * xk_.y + wk0.z * xk_.z + wk0.w * xk_.w;
        ak1 += wk1.x * xk_.x + wk1.y * xk_.y + wk1.z * xk_.z + wk1.w * xk_.w;
        ak2 += wk2.x * xk_.x + wk2.y * xk_.y + wk2.z * xk_.z + wk2.w * xk_.w;
        ak3 += wk3.x * xk_.x + wk3.y * xk_.y + wk3.z * xk_.z + wk3.w * xk_.w;
        av0 += wv0.x * xv_.x + wv0.y * xv_.y + wv0.z * xv_.z + wv0.w * xv_.w;
        av1 += wv1.x * xv_.x + wv1.y * xv_.y + wv1.z * xv_.z + wv1.w * xv_.w;
        av2 += wv2.x * xv_.x + wv2.y * xv_.y + wv2.z * xv_.z + wv2.w * xv_.w;
        av3 += wv3.x * xv_.x + wv3.y * xv_.y + wv3.z * xv_.z + wv3.w * xv_.w;
        ar0 += wr0.x * xr_.x + wr0.y * xr_.y + wr0.z * xr_.z + wr0.w * xr_.w;
        ar1 += wr1.x * xr_.x + wr1.y * xr_.y + wr1.z * xr_.z + wr1.w * xr_.w;
        ar2 += wr2.x * xr_.x + wr2.y * xr_.y + wr2.z * xr_.z + wr2.w * xr_.w;
        ar3 += wr3.x * xr_.x + wr3.y * xr_.y + wr3.z * xr_.z + wr3.w * xr_.w;
    }

#define WREDUCE(s) do { \
        s += __shfl_down(s, 32, 64); s += __shfl_down(s, 16, 64); \
        s += __shfl_down(s,  8, 64); s += __shfl_down(s,  4, 64); \
        s += __shfl_down(s,  2, 64); s += __shfl_down(s,  1, 64); } while (0)
    WREDUCE(ak0); WREDUCE(ak1); WREDUCE(ak2); WREDUCE(ak3);
    WREDUCE(av0); WREDUCE(av1); WREDUCE(av2); WREDUCE(av3);
    WREDUCE(ar0); WREDUCE(ar1); WREDUCE(ar2); WREDUCE(ar3);
#undef WREDUCE

    if (lane == 0) {
        part[0][rg * 4 + 0][h] = ak0; part[0][rg * 4 + 1][h] = ak1;
        part[0][rg * 4 + 2][h] = ak2; part[0][rg * 4 + 3][h] = ak3;
        part[1][rg * 4 + 0][h] = av0; part[1][rg * 4 + 1][h] = av1;
        part[1][rg * 4 + 2][h] = av2; part[1][rg * 4 + 3][h] = av3;
        part[2][rg * 4 + 0][h] = ar0; part[2][rg * 4 + 1][h] = ar1;
        part[2][rg * 4 + 2][h] = ar2; part[2][rg * 4 + 3][h] = ar3;
    }
    __syncthreads();

    if (t < 8) {
        const int i = R + t;
        float kk = part[0][t][0] + part[0][t][1];
        float vv = part[1][t][0] + part[1][t][1];
        float rr = part[2][t][0] + part[2][t][1];

        float a_ = aa[i], b_ = bb[i], p_ = pp[i];

        float ww = time_first[i] + kk;
        float p  = fmaxf(p_, ww);
        float e1 = expf(p_ - p);
        float e2 = expf(ww - p);
        float a  = e1 * a_ + e2 * vv;
        float b  = e1 * b_ + e2;

        float ww2 = p_ + time_decay[i];
        float p2  = fmaxf(ww2, kk);
        float e1b = expf(ww2 - p2);
        float e2b = expf(kk - p2);
        out_sa[i] = e1b * a_ + e2b * vv;
        out_sb[i] = e1b * b_ + e2b;
        out_sp[i] = p2;

        new_state[i] = x[i];

        float r = 1.0f / (1.0f + expf(-rr));
        rwkv[i] = r * (a / b);
    }
}

// ---------------------------------------------------------------------------
// Kernel 2: out = ow @ rwkv. Same structure: block = 8 rows, wave = 4 rows x
// half columns = 4 independent streams.
// ---------------------------------------------------------------------------
__global__ __launch_bounds__(256) void ow_kernel(const float* __restrict__ W,
                                                 const float* __restrict__ xin,
                                                 float* __restrict__ out)
{
    __shared__ float4 xs[C / 4];
    __shared__ float  part[8][2];

    const int t = threadIdx.x;
    const int R = blockIdx.x * 8;

    const float4* x4 = (const float4*)xin;
#pragma unroll
    for (int j = 0; j < 4; ++j) {
        int i = j * 256 + t;
        xs[i] = x4[i];
    }
    __syncthreads();

    const int wave = t >> 6;
    const int lane = t & 63;
    const int h    = wave & 1;
    const int rg   = wave >> 1;
    const int r0   = R + rg * 4;

    const float4* p0 = (const float4*)(W + (size_t)(r0 + 0) * C);
    const float4* p1 = (const float4*)(W + (size_t)(r0 + 1) * C);
    const float4* p2 = (const float4*)(W + (size_t)(r0 + 2) * C);
    const float4* p3 = (const float4*)(W + (size_t)(r0 + 3) * C);

    float a0 = 0.f, a1 = 0.f, a2 = 0.f, a3 = 0.f;
    const int cb0 = h * 512 + lane;
#pragma unroll 2
    for (int it = 0; it < 8; ++it) {
        const int cb = cb0 + it * 64;
        float4 w0 = p0[cb]; float4 w1 = p1[cb]; float4 w2 = p2[cb]; float4 w3 = p3[cb];
        float4 xx = xs[cb];
        a0 += w0.x * xx.x + w0.y * xx.y + w0.z * xx.z + w0.w * xx.w;
        a1 += w1.x * xx.x + w1.y * xx.y + w1.z * xx.z + w1.w * xx.w;
        a2 += w2.x * xx.x + w2.y * xx.y + w2.z * xx.z + w2.w * xx.w;
        a3 += w3.x * xx.x + w3.y * xx.y + w3.z * xx.z + w3.w * xx.w;
    }

#define WREDUCE(s) do { \
        s += __shfl_down(s, 32, 64); s += __shfl_down(s, 16, 64); \
        s += __shfl_down(s,  8, 64); s += __shfl_down(s,  4, 64); \
        s += __shfl_down(s,  2, 64); s += __shfl_down(s,  1, 64); } while (0)
    WREDUCE(a0); WREDUCE(a1); WREDUCE(a2); WREDUCE(a3);
#undef WREDUCE

    if (lane == 0) {
        part[rg * 4 + 0][h] = a0;
        part[rg * 4 + 1][h] = a1;
        part[rg * 4 + 2][h] = a2;
        part[rg * 4 + 3][h] = a3;
    }
    __syncthreads();

    if (t < 8) out[R + t] = part[t][0] + part[t][1];
}

// ---------------------------------------------------------------------------
extern "C" void kernel_launch(void* const* d_in, const int* in_sizes, int n_in,
                              void* d_out, int out_size, void* d_ws, size_t ws_size,
                              hipStream_t stream) {
    const float* x          = (const float*)d_in[0];
    const float* state      = (const float*)d_in[1];
    const float* state_a    = (const float*)d_in[2];
    const float* state_b    = (const float*)d_in[3];
    const float* state_p    = (const float*)d_in[4];
    const float* tmk        = (const float*)d_in[5];
    const float* tmv        = (const float*)d_in[6];
    const float* tmr        = (const float*)d_in[7];
    const float* time_first = (const float*)d_in[8];
    const float* time_decay = (const float*)d_in[9];
    const float* kw         = (const float*)d_in[10];
    const float* vw         = (const float*)d_in[11];
    const float* rw         = (const float*)d_in[12];
    const float* ow         = (const float*)d_in[13];

    float* out       = (float*)d_out;        // [0:C)
    float* new_state = out + C;              // [C:2C)
    float* new_sa    = out + 2 * C;          // [2C:3C)
    float* new_sb    = out + 3 * C;          // [3C:4C)
    float* new_sp    = out + 4 * C;          // [4C:5C)

    float* rwkv = (float*)d_ws;              // [0:C) of workspace

    fused_kvr_wkv_kernel<<<C / 8, 256, 0, stream>>>(
        kw, vw, rw, x, state, tmk, tmv, tmr,
        state_a, state_b, state_p, time_first, time_decay,
        rwkv, new_state, new_sa, new_sb, new_sp);

    ow_kernel<<<C / 8, 256, 0, stream>>>(ow, rwkv, out);
}

// Round 5
// 261.683 us; speedup vs baseline: 1.0143x; 1.0143x over previous
//
#include <hip/hip_runtime.h>
#include <math.h>

#define C 4096
#define NF4 (C / 4)   // float4 elements per row

// ---------------------------------------------------------------------------
// Kernel 1: fused [mix] + [kw@xk, vw@xv, rw@xr] + [wkv] + state outputs.
// Grid: 1024 blocks x 256 (4 waves). Wave w owns row = blockIdx*4+w of ALL
// THREE matrices (sequential m-phases). Per phase: mixed x staged in 16 KiB
// LDS (x-reads use lgkmcnt, decoupled from W's vmcnt), W streamed through a
// 4-deep software pipeline: next 4 float4 global loads issued before current
// group is consumed -> steady ~4-8 KiB W in flight per wave. 16 waves/CU
// resident (16 KiB LDS, 4 blocks/CU) -> ~80+ KB/CU in flight.
// Since the wave ends phase m holding its row's kk/vv/rr, wkv is computed
// in-register by lane 0 — no intermediate buffers, no extra kernel.
// ---------------------------------------------------------------------------
__global__ __launch_bounds__(256) void gemv_kvr_wkv_kernel(
    const float* __restrict__ kw, const float* __restrict__ vw, const float* __restrict__ rw,
    const float* __restrict__ x, const float* __restrict__ state,
    const float* __restrict__ tmk, const float* __restrict__ tmv, const float* __restrict__ tmr,
    const float* __restrict__ aa, const float* __restrict__ bb, const float* __restrict__ pp,
    const float* __restrict__ time_first, const float* __restrict__ time_decay,
    float* __restrict__ rwkv, float* __restrict__ new_state,
    float* __restrict__ out_sa, float* __restrict__ out_sb, float* __restrict__ out_sp)
{
    __shared__ float4 xs[NF4];   // 16 KiB: mixed vector for the current matrix phase

    const int t    = threadIdx.x;
    const int wave = t >> 6;
    const int lane = t & 63;
    const int row  = blockIdx.x * 4 + wave;

    const float4* x4 = (const float4*)x;
    const float4* s4 = (const float4*)state;

    float kk_r = 0.f, vv_r = 0.f, rr_r = 0.f;

#pragma unroll
    for (int m = 0; m < 3; ++m) {
        const float* W  = (m == 0) ? kw  : (m == 1) ? vw  : rw;
        const float* Tm = (m == 0) ? tmk : (m == 1) ? tmv : tmr;

        // Stage mixed x for this matrix: xm = s + tm*(x - s)
        __syncthreads();   // previous phase's xs readers must be done
        const float4* t4 = (const float4*)Tm;
#pragma unroll
        for (int j = 0; j < 4; ++j) {
            int i = j * 256 + t;
            float4 xi = x4[i], si = s4[i], ti = t4[i];
            float4 r;
            r.x = si.x + ti.x * (xi.x - si.x);
            r.y = si.y + ti.y * (xi.y - si.y);
            r.z = si.z + ti.z * (xi.z - si.z);
            r.w = si.w + ti.w * (xi.w - si.w);
            xs[i] = r;
        }
        __syncthreads();

        const float4* Wp = (const float4*)(W + (size_t)row * C);

        // 16 chunks of 64 float4, as 4 groups of 4, software-pipelined.
        float4 w0 = Wp[lane +   0];
        float4 w1 = Wp[lane +  64];
        float4 w2 = Wp[lane + 128];
        float4 w3 = Wp[lane + 192];
        float a0 = 0.f, a1 = 0.f, a2 = 0.f, a3 = 0.f;
#pragma unroll
        for (int g = 0; g < 4; ++g) {
            const int b = g * 256 + lane;
            float4 n0 = make_float4(0.f, 0.f, 0.f, 0.f);
            float4 n1 = n0, n2 = n0, n3 = n0;
            if (g < 3) {   // issue next group's loads before consuming current
                n0 = Wp[b + 256];
                n1 = Wp[b + 320];
                n2 = Wp[b + 384];
                n3 = Wp[b + 448];
            }
            float4 x0 = xs[b], x1 = xs[b + 64], x2 = xs[b + 128], x3 = xs[b + 192];
            a0 += w0.x * x0.x + w0.y * x0.y + w0.z * x0.z + w0.w * x0.w;
            a1 += w1.x * x1.x + w1.y * x1.y + w1.z * x1.z + w1.w * x1.w;
            a2 += w2.x * x2.x + w2.y * x2.y + w2.z * x2.z + w2.w * x2.w;
            a3 += w3.x * x3.x + w3.y * x3.y + w3.z * x3.z + w3.w * x3.w;
            w0 = n0; w1 = n1; w2 = n2; w3 = n3;
        }
        float s = (a0 + a1) + (a2 + a3);
        s += __shfl_down(s, 32, 64);
        s += __shfl_down(s, 16, 64);
        s += __shfl_down(s,  8, 64);
        s += __shfl_down(s,  4, 64);
        s += __shfl_down(s,  2, 64);
        s += __shfl_down(s,  1, 64);
        if (m == 0) kk_r = s; else if (m == 1) vv_r = s; else rr_r = s;
    }

    // WKV elementwise for this wave's row (lane 0 holds the reduced sums).
    if (lane == 0) {
        const int i = row;
        float kk = kk_r, vv = vv_r, rr = rr_r;
        float a_ = aa[i], b_ = bb[i], p_ = pp[i];

        float ww = time_first[i] + kk;
        float p  = fmaxf(p_, ww);
        float e1 = expf(p_ - p);
        float e2 = expf(ww - p);
        float a  = e1 * a_ + e2 * vv;
        float b  = e1 * b_ + e2;

        float ww2 = p_ + time_decay[i];
        float p2  = fmaxf(ww2, kk);
        float e1b = expf(ww2 - p2);
        float e2b = expf(kk - p2);
        out_sa[i] = e1b * a_ + e2b * vv;
        out_sb[i] = e1b * b_ + e2b;
        out_sp[i] = p2;

        new_state[i] = x[i];

        float r = 1.0f / (1.0f + expf(-rr));
        rwkv[i] = r * (a / b);
    }
}

// ---------------------------------------------------------------------------
// Kernel 2: out = ow @ rwkv. Same pipelined GEMV core, single matrix.
// ---------------------------------------------------------------------------
__global__ __launch_bounds__(256) void gemv_ow_kernel(const float* __restrict__ W,
                                                      const float* __restrict__ xin,
                                                      float* __restrict__ out)
{
    __shared__ float4 xs[NF4];

    const int t    = threadIdx.x;
    const int wave = t >> 6;
    const int lane = t & 63;
    const int row  = blockIdx.x * 4 + wave;

    const float4* x4 = (const float4*)xin;
#pragma unroll
    for (int j = 0; j < 4; ++j) {
        int i = j * 256 + t;
        xs[i] = x4[i];
    }
    __syncthreads();

    const float4* Wp = (const float4*)(W + (size_t)row * C);

    float4 w0 = Wp[lane +   0];
    float4 w1 = Wp[lane +  64];
    float4 w2 = Wp[lane + 128];
    float4 w3 = Wp[lane + 192];
    float a0 = 0.f, a1 = 0.f, a2 = 0.f, a3 = 0.f;
#pragma unroll
    for (int g = 0; g < 4; ++g) {
        const int b = g * 256 + lane;
        float4 n0 = make_float4(0.f, 0.f, 0.f, 0.f);
        float4 n1 = n0, n2 = n0, n3 = n0;
        if (g < 3) {
            n0 = Wp[b + 256];
            n1 = Wp[b + 320];
            n2 = Wp[b + 384];
            n3 = Wp[b + 448];
        }
        float4 x0 = xs[b], x1 = xs[b + 64], x2 = xs[b + 128], x3 = xs[b + 192];
        a0 += w0.x * x0.x + w0.y * x0.y + w0.z * x0.z + w0.w * x0.w;
        a1 += w1.x * x1.x + w1.y * x1.y + w1.z * x1.z + w1.w * x1.w;
        a2 += w2.x * x2.x + w2.y * x2.y + w2.z * x2.z + w2.w * x2.w;
        a3 += w3.x * x3.x + w3.y * x3.y + w3.z * x3.z + w3.w * x3.w;
        w0 = n0; w1 = n1; w2 = n2; w3 = n3;
    }
    float s = (a0 + a1) + (a2 + a3);
    s += __shfl_down(s, 32, 64);
    s += __shfl_down(s, 16, 64);
    s += __shfl_down(s,  8, 64);
    s += __shfl_down(s,  4, 64);
    s += __shfl_down(s,  2, 64);
    s += __shfl_down(s,  1, 64);
    if (lane == 0) out[row] = s;
}

// ---------------------------------------------------------------------------
extern "C" void kernel_launch(void* const* d_in, const int* in_sizes, int n_in,
                              void* d_out, int out_size, void* d_ws, size_t ws_size,
                              hipStream_t stream) {
    const float* x          = (const float*)d_in[0];
    const float* state      = (const float*)d_in[1];
    const float* state_a    = (const float*)d_in[2];
    const float* state_b    = (const float*)d_in[3];
    const float* state_p    = (const float*)d_in[4];
    const float* tmk        = (const float*)d_in[5];
    const float* tmv        = (const float*)d_in[6];
    const float* tmr        = (const float*)d_in[7];
    const float* time_first = (const float*)d_in[8];
    const float* time_decay = (const float*)d_in[9];
    const float* kw         = (const float*)d_in[10];
    const float* vw         = (const float*)d_in[11];
    const float* rw         = (const float*)d_in[12];
    const float* ow         = (const float*)d_in[13];

    float* out       = (float*)d_out;        // [0:C)
    float* new_state = out + C;              // [C:2C)
    float* new_sa    = out + 2 * C;          // [2C:3C)
    float* new_sb    = out + 3 * C;          // [3C:4C)
    float* new_sp    = out + 4 * C;          // [4C:5C)

    float* rwkv = (float*)d_ws;              // [0:C) of workspace

    gemv_kvr_wkv_kernel<<<C / 4, 256, 0, stream>>>(
        kw, vw, rw, x, state, tmk, tmv, tmr,
        state_a, state_b, state_p, time_first, time_decay,
        rwkv, new_state, new_sa, new_sb, new_sp);

    gemv_ow_kernel<<<C / 4, 256, 0, stream>>>(ow, rwkv, out);
}